// Round 1
// baseline (2767.851 us; speedup 1.0000x reference)
//
#include <hip/hip_runtime.h>

#define NCLS 1000
#define DIM 256
#define TEMP 0.07f
#define EPSN 1e-12f

// ---------------- K1: segment sum (+ optional per-row logit scale) -------------
template<bool WITH_SCALE>
__global__ __launch_bounds__(256) void seg_sum_kernel(
    const float* __restrict__ feats, const int* __restrict__ labels,
    float* __restrict__ sums, float* __restrict__ counts,
    float* __restrict__ scale, int N) {
  const int lane = threadIdx.x & 63;
  const int wid  = (blockIdx.x * blockDim.x + threadIdx.x) >> 6;
  const int nw   = (gridDim.x * blockDim.x) >> 6;
  for (int r = wid; r < N; r += nw) {
    const int c = labels[r];
    const float* row = feats + (size_t)r * DIM;
    float v0 = row[lane];
    float v1 = row[lane + 64];
    float v2 = row[lane + 128];
    float v3 = row[lane + 192];
    float* dst = sums + (size_t)c * DIM;
    atomicAdd(dst + lane,        v0);
    atomicAdd(dst + lane + 64,   v1);
    atomicAdd(dst + lane + 128,  v2);
    atomicAdd(dst + lane + 192,  v3);
    if (WITH_SCALE) {
      float ss = v0*v0 + v1*v1 + v2*v2 + v3*v3;
      #pragma unroll
      for (int o = 1; o < 64; o <<= 1) ss += __shfl_xor(ss, o);
      if (lane == 0) scale[r] = 1.0f / (TEMP * fmaxf(sqrtf(ss), EPSN));
    }
    if (lane == 0) atomicAdd(counts + c, 1.0f);
  }
}

// ---------------- K2: mean + L2-normalize prototypes ---------------------------
__global__ __launch_bounds__(256) void finalize_kernel(
    const float* __restrict__ sums, const float* __restrict__ counts,
    float* __restrict__ mean_out,  // nullable; d_out is only 8B-aligned -> scalar stores
    float* __restrict__ pn) {
  const int lane = threadIdx.x & 63;
  const int wid  = (blockIdx.x * blockDim.x + threadIdx.x) >> 6;
  if (wid >= NCLS) return;
  const float inv = 1.0f / fmaxf(counts[wid], 1.0f);
  float4 s = ((const float4*)(sums + (size_t)wid * DIM))[lane];
  float4 mm;
  mm.x = s.x * inv; mm.y = s.y * inv; mm.z = s.z * inv; mm.w = s.w * inv;
  if (mean_out) {
    float* mo = mean_out + (size_t)wid * DIM + lane * 4;
    mo[0] = mm.x; mo[1] = mm.y; mo[2] = mm.z; mo[3] = mm.w;
  }
  float ss = mm.x*mm.x + mm.y*mm.y + mm.z*mm.z + mm.w*mm.w;
  #pragma unroll
  for (int o = 1; o < 64; o <<= 1) ss += __shfl_xor(ss, o);
  const float innv = 1.0f / fmaxf(sqrtf(ss), EPSN);
  float4 p;
  p.x = mm.x * innv; p.y = mm.y * innv; p.z = mm.z * innv; p.w = mm.w * innv;
  ((float4*)(pn + (size_t)wid * DIM))[lane] = p;
}

// ---------------- K3: structure matrices + struct loss -------------------------
__global__ __launch_bounds__(256) void struct_kernel(
    const float* __restrict__ spn, const float* __restrict__ tpn,
    float* __restrict__ out_struct, float* __restrict__ acc) {
  __shared__ float Ai[16][260];
  __shared__ float Bj[16][260];
  __shared__ float red[256];
  const int t  = threadIdx.x;
  const int i0 = blockIdx.y * 16, j0 = blockIdx.x * 16;
  const int ti = t >> 4, tj = t & 15;
  float s = 0.0f, tt = 0.0f;
  for (int mtx = 0; mtx < 2; mtx++) {
    const float* mat = mtx ? tpn : spn;
    __syncthreads();
    #pragma unroll
    for (int q = 0; q < 4; q++) {
      int idx = t + 256 * q;
      int rr = idx >> 6, c4 = idx & 63;
      float4 z = make_float4(0.f, 0.f, 0.f, 0.f);
      float4 a = (i0 + rr < NCLS) ? ((const float4*)(mat + (size_t)(i0 + rr) * DIM))[c4] : z;
      float4 b = (j0 + rr < NCLS) ? ((const float4*)(mat + (size_t)(j0 + rr) * DIM))[c4] : z;
      *(float4*)&Ai[rr][c4 * 4] = a;
      *(float4*)&Bj[rr][c4 * 4] = b;
    }
    __syncthreads();
    float d = 0.0f;
    #pragma unroll 8
    for (int k = 0; k < DIM; k++) d = fmaf(Ai[ti][k], Bj[tj][k], d);
    if (mtx == 0) s = d; else tt = d;
  }
  const int gi = i0 + ti, gj = j0 + tj;
  float d2 = 0.0f;
  if (gi < NCLS && gj < NCLS) {
    out_struct[gi * NCLS + gj] = s;
    float df = s - tt;
    d2 = df * df;
  }
  red[t] = d2;
  __syncthreads();
  for (int o = 128; o > 0; o >>= 1) { if (t < o) red[t] += red[t + o]; __syncthreads(); }
  if (t == 0) atomicAdd(acc, red[0]);
}

// ---------------- K4: contrastive loss (fused GEMM + online logsumexp) ---------
__global__ __launch_bounds__(256) void contrast_kernel(
    const float* __restrict__ feats, const int* __restrict__ labels,
    const float* __restrict__ pn, const float* __restrict__ scale,
    float* __restrict__ acc, int N) {
  __shared__ float As[16][132];
  __shared__ float Bs[16][132];
  __shared__ float red[256];
  const int t  = threadIdx.x;
  const int tx = t & 15, ty = t >> 4;
  const int row0 = blockIdx.x * 128;
  float m[8], ssum[8], lab[8], scl[8];
  int lbl[8];
  #pragma unroll
  for (int i = 0; i < 8; i++) {
    m[i] = -1e30f; ssum[i] = 0.0f; lab[i] = 0.0f;
    int r = row0 + ty * 8 + i;
    scl[i] = (r < N) ? scale[r] : 0.0f;
    lbl[i] = (r < N) ? labels[r] : -1;
  }
  for (int pt = 0; pt < 8; pt++) {
    const int p0 = pt * 128;
    float l[8][8];
    #pragma unroll
    for (int i = 0; i < 8; i++)
      #pragma unroll
      for (int j = 0; j < 8; j++) l[i][j] = 0.0f;
    for (int kc = 0; kc < DIM; kc += 16) {
      __syncthreads();
      #pragma unroll
      for (int q = 0; q < 2; q++) {
        int idx = t + 256 * q;
        int kq = idx & 3, rr = idx >> 2;
        float4 z = make_float4(0.f, 0.f, 0.f, 0.f);
        int gr = row0 + rr;
        float4 a = (gr < N) ? *(const float4*)(feats + (size_t)gr * DIM + kc + kq * 4) : z;
        As[kq * 4 + 0][rr] = a.x; As[kq * 4 + 1][rr] = a.y;
        As[kq * 4 + 2][rr] = a.z; As[kq * 4 + 3][rr] = a.w;
        int gp = p0 + rr;
        float4 b = (gp < NCLS) ? *(const float4*)(pn + (size_t)gp * DIM + kc + kq * 4) : z;
        Bs[kq * 4 + 0][rr] = b.x; Bs[kq * 4 + 1][rr] = b.y;
        Bs[kq * 4 + 2][rr] = b.z; Bs[kq * 4 + 3][rr] = b.w;
      }
      __syncthreads();
      #pragma unroll
      for (int kk = 0; kk < 16; kk++) {
        float a[8], b[8];
        *(float4*)&a[0] = *(const float4*)&As[kk][ty * 8];
        *(float4*)&a[4] = *(const float4*)&As[kk][ty * 8 + 4];
        *(float4*)&b[0] = *(const float4*)&Bs[kk][tx * 8];
        *(float4*)&b[4] = *(const float4*)&Bs[kk][tx * 8 + 4];
        #pragma unroll
        for (int i = 0; i < 8; i++)
          #pragma unroll
          for (int j = 0; j < 8; j++)
            l[i][j] = fmaf(a[i], b[j], l[i][j]);
      }
    }
    // online logsumexp update across the 16 tx-threads sharing each row
    #pragma unroll
    for (int i = 0; i < 8; i++) {
      float lv[8];
      float tmax = -1e30f;
      #pragma unroll
      for (int j = 0; j < 8; j++) {
        int gc = p0 + tx * 8 + j;
        float lg = (gc < NCLS) ? l[i][j] * scl[i] : -1e30f;
        lv[j] = lg;
        tmax = fmaxf(tmax, lg);
        lab[i] += (gc == lbl[i]) ? lg : 0.0f;
      }
      #pragma unroll
      for (int o = 1; o < 16; o <<= 1) tmax = fmaxf(tmax, __shfl_xor(tmax, o));
      float mn = fmaxf(m[i], tmax);
      float f  = __expf(m[i] - mn);
      float ls = 0.0f;
      #pragma unroll
      for (int j = 0; j < 8; j++) ls += __expf(lv[j] - mn);
      #pragma unroll
      for (int o = 1; o < 16; o <<= 1) ls += __shfl_xor(ls, o);
      ssum[i] = ssum[i] * f + ls;
      m[i] = mn;
    }
  }
  float loss = 0.0f;
  #pragma unroll
  for (int i = 0; i < 8; i++) {
    float lb = lab[i];
    #pragma unroll
    for (int o = 1; o < 16; o <<= 1) lb += __shfl_xor(lb, o);
    int r = row0 + ty * 8 + i;
    if (tx == 0 && r < N) loss += m[i] + __logf(ssum[i]) - lb;
  }
  red[t] = loss;
  __syncthreads();
  for (int o = 128; o > 0; o >>= 1) { if (t < o) red[t] += red[t + o]; __syncthreads(); }
  if (t == 0) atomicAdd(acc, red[0]);
}

// ---------------- K5: scalars ---------------------------------------------------
__global__ void final_kernel(const float* __restrict__ acc, float* __restrict__ out, int N) {
  out[0] = acc[0] * (1.0f / (float)(NCLS * NCLS));
  out[1] = acc[1] / (float)N;
}

extern "C" void kernel_launch(void* const* d_in, const int* in_sizes, int n_in,
                              void* d_out, int out_size, void* d_ws, size_t ws_size,
                              hipStream_t stream) {
  const float* src_feats  = (const float*)d_in[0];
  const int*   src_labels = (const int*)d_in[1];
  const float* tgt_feats  = (const float*)d_in[2];
  const int*   tgt_labels = (const int*)d_in[3];
  const int N = in_sizes[0] / DIM;

  // ws layout (floats):
  // [0,256000)        src_sums
  // [256000,512000)   tgt_sums
  // [512000,513000)   src_counts
  // [513000,514000)   tgt_counts
  // [514000,514002)   acc: [0]=struct sq-sum, [1]=contrast sum
  // [514016,770016)   src_pn (normalized src protos)
  // [770016,1026016)  tgt_pn
  // [1026016, +N)     scale (1/(T*||f_i||)) for src rows
  float* ws         = (float*)d_ws;
  float* src_sums   = ws;
  float* tgt_sums   = ws + 256000;
  float* src_counts = ws + 512000;
  float* tgt_counts = ws + 513000;
  float* acc        = ws + 514000;
  float* src_pn     = ws + 514016;
  float* tgt_pn     = ws + 770016;
  float* scale      = ws + 1026016;

  float* out_f      = (float*)d_out;
  float* out_protos = out_f + 2;
  float* out_struct = out_f + 2 + NCLS * DIM;

  hipMemsetAsync(d_ws, 0, (size_t)514002 * sizeof(float), stream);

  seg_sum_kernel<true ><<<2048, 256, 0, stream>>>(src_feats, src_labels, src_sums, src_counts, scale, N);
  seg_sum_kernel<false><<<2048, 256, 0, stream>>>(tgt_feats, tgt_labels, tgt_sums, tgt_counts, nullptr, N);

  finalize_kernel<<<250, 256, 0, stream>>>(src_sums, src_counts, out_protos, src_pn);
  finalize_kernel<<<250, 256, 0, stream>>>(tgt_sums, tgt_counts, nullptr,    tgt_pn);

  dim3 sgrid(63, 63);
  struct_kernel<<<sgrid, 256, 0, stream>>>(src_pn, tgt_pn, out_struct, acc);

  int cblocks = (N + 127) / 128;
  contrast_kernel<<<cblocks, 256, 0, stream>>>(src_feats, src_labels, src_pn, scale, acc + 1, N);

  final_kernel<<<1, 1, 0, stream>>>(acc, out_f, N);
}

// Round 2
// 732.054 us; speedup vs baseline: 3.7809x; 3.7809x over previous
//
#include <hip/hip_runtime.h>

#define NCLS 1000
#define DIM 256
#define INV_TEMP 14.285714285714286f
#define LSE_C 16.0f

typedef __attribute__((ext_vector_type(8))) short short8;
typedef __attribute__((ext_vector_type(4))) float f32x4;

__device__ __forceinline__ short f2bf(float f) {
  unsigned u = __float_as_uint(f);
  unsigned r = u + 0x7fffu + ((u >> 16) & 1u);
  return (short)(r >> 16);
}

// ---------------- K1: per-class gather + mean + normalize (no atomics) ---------
__global__ __launch_bounds__(256) void proto_kernel(
    const float* __restrict__ sf, const int* __restrict__ sl,
    const float* __restrict__ tf, const int* __restrict__ tl, int N,
    float* __restrict__ mean_out, float* __restrict__ spn, float* __restrict__ tpn,
    unsigned short* __restrict__ pbf) {
  const int bid = blockIdx.x;
  const int side = (bid >= NCLS) ? 1 : 0;
  const int c = bid - side * NCLS;
  const float* feats = side ? tf : sf;
  const int* labels = side ? tl : sl;
  float* pn = side ? tpn : spn;

  __shared__ int list[4096];
  __shared__ int s_cnt;
  __shared__ float s_red[4];
  const int t = threadIdx.x;
  if (t == 0) s_cnt = 0;
  __syncthreads();

  const int n4 = N >> 2;
  for (int i = t; i < n4; i += 256) {
    int4 lb = ((const int4*)labels)[i];
    if (lb.x == c) { int p = atomicAdd(&s_cnt, 1); if (p < 4096) list[p] = 4*i; }
    if (lb.y == c) { int p = atomicAdd(&s_cnt, 1); if (p < 4096) list[p] = 4*i+1; }
    if (lb.z == c) { int p = atomicAdd(&s_cnt, 1); if (p < 4096) list[p] = 4*i+2; }
    if (lb.w == c) { int p = atomicAdd(&s_cnt, 1); if (p < 4096) list[p] = 4*i+3; }
  }
  for (int i = (n4 << 2) + t; i < N; i += 256) {
    if (labels[i] == c) { int p = atomicAdd(&s_cnt, 1); if (p < 4096) list[p] = i; }
  }
  __syncthreads();
  const int m = min(s_cnt, 4096);

  // each thread owns column t
  float s0 = 0.f, s1 = 0.f, s2 = 0.f, s3 = 0.f;
  int i = 0;
  for (; i + 4 <= m; i += 4) {
    s0 += feats[(size_t)list[i]     * DIM + t];
    s1 += feats[(size_t)list[i + 1] * DIM + t];
    s2 += feats[(size_t)list[i + 2] * DIM + t];
    s3 += feats[(size_t)list[i + 3] * DIM + t];
  }
  for (; i < m; i++) s0 += feats[(size_t)list[i] * DIM + t];
  float sum = (s0 + s1) + (s2 + s3);
  float mean = sum / fmaxf((float)m, 1.0f);
  if (!side) mean_out[(size_t)c * DIM + t] = mean;

  float ss = mean * mean;
  #pragma unroll
  for (int o = 1; o < 64; o <<= 1) ss += __shfl_xor(ss, o);
  if ((t & 63) == 0) s_red[t >> 6] = ss;
  __syncthreads();
  float tot = s_red[0] + s_red[1] + s_red[2] + s_red[3];
  float innv = 1.0f / fmaxf(sqrtf(tot), 1e-12f);
  float p = mean * innv;
  pn[(size_t)c * DIM + t] = p;
  if (!side) pbf[(size_t)c * DIM + t] = (unsigned short)f2bf(p);
}

// ---------------- K2: structure matrices + struct loss (fp32, 64x64 tiles) -----
__global__ __launch_bounds__(256) void struct_kernel(
    const float* __restrict__ spn, const float* __restrict__ tpn,
    float* __restrict__ out_struct, float* __restrict__ acc) {
  __shared__ float Sa[16][68], Sb[16][68], Ta[16][68], Tb[16][68];
  __shared__ float red[256];
  const int t = threadIdx.x;
  const int tx = t & 15, ty = t >> 4;
  const int i0 = blockIdx.y * 64, j0 = blockIdx.x * 64;
  float cs[4][4], cg[4][4];
  #pragma unroll
  for (int a = 0; a < 4; a++)
    #pragma unroll
    for (int b = 0; b < 4; b++) { cs[a][b] = 0.f; cg[a][b] = 0.f; }

  const int srow = t >> 2;
  const int skq = (t & 3) * 4;
  for (int k0 = 0; k0 < DIM; k0 += 16) {
    __syncthreads();
    {
      float4 z = make_float4(0.f, 0.f, 0.f, 0.f);
      int ra = i0 + srow, rb = j0 + srow;
      float4 va = (ra < NCLS) ? *(const float4*)(spn + (size_t)ra * DIM + k0 + skq) : z;
      float4 vb = (rb < NCLS) ? *(const float4*)(spn + (size_t)rb * DIM + k0 + skq) : z;
      float4 wa = (ra < NCLS) ? *(const float4*)(tpn + (size_t)ra * DIM + k0 + skq) : z;
      float4 wb = (rb < NCLS) ? *(const float4*)(tpn + (size_t)rb * DIM + k0 + skq) : z;
      Sa[skq+0][srow]=va.x; Sa[skq+1][srow]=va.y; Sa[skq+2][srow]=va.z; Sa[skq+3][srow]=va.w;
      Sb[skq+0][srow]=vb.x; Sb[skq+1][srow]=vb.y; Sb[skq+2][srow]=vb.z; Sb[skq+3][srow]=vb.w;
      Ta[skq+0][srow]=wa.x; Ta[skq+1][srow]=wa.y; Ta[skq+2][srow]=wa.z; Ta[skq+3][srow]=wa.w;
      Tb[skq+0][srow]=wb.x; Tb[skq+1][srow]=wb.y; Tb[skq+2][srow]=wb.z; Tb[skq+3][srow]=wb.w;
    }
    __syncthreads();
    #pragma unroll
    for (int k = 0; k < 16; k++) {
      float a[4], b[4], c[4], d[4];
      *(float4*)a = *(const float4*)&Sa[k][ty * 4];
      *(float4*)b = *(const float4*)&Sb[k][tx * 4];
      *(float4*)c = *(const float4*)&Ta[k][ty * 4];
      *(float4*)d = *(const float4*)&Tb[k][tx * 4];
      #pragma unroll
      for (int ii = 0; ii < 4; ii++)
        #pragma unroll
        for (int jj = 0; jj < 4; jj++) {
          cs[ii][jj] = fmaf(a[ii], b[jj], cs[ii][jj]);
          cg[ii][jj] = fmaf(c[ii], d[jj], cg[ii][jj]);
        }
    }
  }
  float d2 = 0.f;
  #pragma unroll
  for (int ii = 0; ii < 4; ii++) {
    int gi = i0 + ty * 4 + ii;
    if (gi < NCLS) {
      #pragma unroll
      for (int jj = 0; jj < 4; jj++) {
        int gj = j0 + tx * 4 + jj;
        if (gj < NCLS) {
          out_struct[(size_t)gi * NCLS + gj] = cs[ii][jj];
          float df = cs[ii][jj] - cg[ii][jj];
          d2 += df * df;
        }
      }
    }
  }
  red[t] = d2;
  __syncthreads();
  for (int o = 128; o > 0; o >>= 1) { if (t < o) red[t] += red[t + o]; __syncthreads(); }
  if (t == 0) atomicAdd(acc, red[0]);
}

// ---------------- K3: contrastive loss — bf16 MFMA GEMM + flat LSE -------------
__global__ __launch_bounds__(256, 3) void contrast_kernel(
    const float* __restrict__ feats, const int* __restrict__ labels,
    const unsigned short* __restrict__ pbf,
    float* __restrict__ acc_out, int N) {
  __shared__ float red[256];
  const int t = threadIdx.x;
  const int lane = t & 63, w = t >> 6;
  const int row0 = blockIdx.x * 128 + w * 32;
  const int lx = lane & 15, lg = lane >> 4;

  short8 af[2][8];
  float scls[2][4];
  int lblS[2][4];
  const float4 z4 = make_float4(0.f, 0.f, 0.f, 0.f);

  #pragma unroll
  for (int rf = 0; rf < 2; rf++) {
    int r = row0 + rf * 16 + lx;
    bool v = r < N;
    const float* rp = feats + (size_t)r * DIM + (lg << 3);
    float n2 = 0.f;
    #pragma unroll
    for (int kf = 0; kf < 8; kf++) {
      float4 x = v ? *(const float4*)(rp + kf * 32) : z4;
      float4 y = v ? *(const float4*)(rp + kf * 32 + 4) : z4;
      n2 += x.x*x.x + x.y*x.y + x.z*x.z + x.w*x.w
          + y.x*y.x + y.y*y.y + y.z*y.z + y.w*y.w;
      short8 f;
      f[0] = f2bf(x.x); f[1] = f2bf(x.y); f[2] = f2bf(x.z); f[3] = f2bf(x.w);
      f[4] = f2bf(y.x); f[5] = f2bf(y.y); f[6] = f2bf(y.z); f[7] = f2bf(y.w);
      af[rf][kf] = f;
    }
    n2 += __shfl_xor(n2, 16);
    n2 += __shfl_xor(n2, 32);
    float scl = INV_TEMP * rsqrtf(fmaxf(n2, 1e-30f));
    #pragma unroll
    for (int reg = 0; reg < 4; reg++) {
      int src = (lg << 2) | reg;
      scls[rf][reg] = __shfl(scl, src);
      int row = row0 + rf * 16 + src;
      lblS[rf][reg] = (row < N) ? labels[row] : -1;
    }
  }

  float sSt[2][4], labS[2][4];
  #pragma unroll
  for (int rf = 0; rf < 2; rf++)
    #pragma unroll
    for (int reg = 0; reg < 4; reg++) { sSt[rf][reg] = 0.f; labS[rf][reg] = 0.f; }

  // loop over 63 column fragments of 16 prototypes (cols 0..1007, bf16-padded)
  for (int cf = 0; cf < 63; cf++) {
    const int col = cf * 16 + lx;
    const unsigned short* bp = pbf + (size_t)col * DIM + (lg << 3);
    short8 b[8];
    #pragma unroll
    for (int kf = 0; kf < 8; kf++) b[kf] = *(const short8*)(bp + kf * 32);
    f32x4 d0 = {0.f, 0.f, 0.f, 0.f};
    f32x4 d1 = {0.f, 0.f, 0.f, 0.f};
    #pragma unroll
    for (int kf = 0; kf < 8; kf++) {
      d0 = __builtin_amdgcn_mfma_f32_16x16x32_bf16(af[0][kf], b[kf], d0, 0, 0, 0);
      d1 = __builtin_amdgcn_mfma_f32_16x16x32_bf16(af[1][kf], b[kf], d1, 0, 0, 0);
    }
    const bool cv = col < NCLS;
    #pragma unroll
    for (int reg = 0; reg < 4; reg++) {
      float l0 = d0[reg] * scls[0][reg];
      float l1 = d1[reg] * scls[1][reg];
      sSt[0][reg] += cv ? __expf(l0 - LSE_C) : 0.f;
      sSt[1][reg] += cv ? __expf(l1 - LSE_C) : 0.f;
      labS[0][reg] += (cv && col == lblS[0][reg]) ? l0 : 0.f;
      labS[1][reg] += (cv && col == lblS[1][reg]) ? l1 : 0.f;
    }
  }

  float wloss = 0.f;
  #pragma unroll
  for (int rf = 0; rf < 2; rf++)
    #pragma unroll
    for (int reg = 0; reg < 4; reg++) {
      float s = sSt[rf][reg], lb = labS[rf][reg];
      #pragma unroll
      for (int o = 1; o < 16; o <<= 1) { s += __shfl_xor(s, o); lb += __shfl_xor(lb, o); }
      int row = row0 + rf * 16 + (lg << 2) + reg;
      if (lx == 0 && row < N) wloss += LSE_C + __logf(s) - lb;
    }

  red[t] = wloss;
  __syncthreads();
  for (int o = 128; o > 0; o >>= 1) { if (t < o) red[t] += red[t + o]; __syncthreads(); }
  if (t == 0) atomicAdd(acc_out, red[0]);
}

// ---------------- K4: scalars ---------------------------------------------------
__global__ void final_kernel(const float* __restrict__ acc, float* __restrict__ out, int N) {
  out[0] = acc[0] * (1.0f / (float)(NCLS * NCLS));
  out[1] = acc[1] / (float)N;
}

extern "C" void kernel_launch(void* const* d_in, const int* in_sizes, int n_in,
                              void* d_out, int out_size, void* d_ws, size_t ws_size,
                              hipStream_t stream) {
  const float* src_feats  = (const float*)d_in[0];
  const int*   src_labels = (const int*)d_in[1];
  const float* tgt_feats  = (const float*)d_in[2];
  const int*   tgt_labels = (const int*)d_in[3];
  const int N = in_sizes[0] / DIM;

  // ws layout (floats):
  // [0,2)            acc: [0]=struct sq-sum, [1]=contrast sum
  // [16,256016)      src_pn
  // [256016,512016)  tgt_pn
  // [512016,+129024) pbf: 1008x256 bf16 (ushort)
  float* ws = (float*)d_ws;
  float* acc    = ws;
  float* src_pn = ws + 16;
  float* tgt_pn = ws + 256016;
  unsigned short* pbf = (unsigned short*)(ws + 512016);

  float* out_f      = (float*)d_out;
  float* out_protos = out_f + 2;
  float* out_struct = out_f + 2 + NCLS * DIM;

  hipMemsetAsync(acc, 0, 2 * sizeof(float), stream);
  hipMemsetAsync(pbf + (size_t)NCLS * DIM, 0, 8 * DIM * sizeof(unsigned short), stream);

  proto_kernel<<<2 * NCLS, 256, 0, stream>>>(src_feats, src_labels, tgt_feats, tgt_labels,
                                             N, out_protos, src_pn, tgt_pn, pbf);

  dim3 sgrid(16, 16);
  struct_kernel<<<sgrid, 256, 0, stream>>>(src_pn, tgt_pn, out_struct, acc);

  int cblocks = (N + 127) / 128;
  contrast_kernel<<<cblocks, 256, 0, stream>>>(src_feats, src_labels, pbf, acc + 1, N);

  final_kernel<<<1, 1, 0, stream>>>(acc, out_f, N);
}

// Round 3
// 562.503 us; speedup vs baseline: 4.9206x; 1.3014x over previous
//
#include <hip/hip_runtime.h>

#define NCLS 1000
#define NCOL 1008
#define NTILE 63
#define DIM 256
#define INV_TEMP 14.285714285714286f
#define LSE_C 16.0f
#define PADC 9.0028140e-07f  // 8 * exp(-16): pad-column contribution

typedef __attribute__((ext_vector_type(8))) short short8;
typedef __attribute__((ext_vector_type(4))) float f32x4;

__device__ __forceinline__ short f2bf(float f) {
  unsigned u = __float_as_uint(f);
  unsigned r = u + 0x7fffu + ((u >> 16) & 1u);
  return (short)(r >> 16);
}

__device__ __forceinline__ void gload_lds16(const void* g, void* l) {
  __builtin_amdgcn_global_load_lds(
      (const __attribute__((address_space(1))) unsigned int*)g,
      (__attribute__((address_space(3))) unsigned int*)l, 16, 0, 0);
}

// ---------------- K1: per-class gather + mean + normalize (4 classes/block) ----
#define CPB 4
#define LCAP 1536
__global__ __launch_bounds__(256) void proto_kernel(
    const float* __restrict__ sf, const int* __restrict__ sl,
    const float* __restrict__ tf, const int* __restrict__ tl, int N,
    float* __restrict__ mean_out, float* __restrict__ spn, float* __restrict__ tpn,
    unsigned short* __restrict__ pbf) {
  const int bid = blockIdx.x;
  const int side = (bid >= NCLS / CPB) ? 1 : 0;
  const int c0 = (bid - side * (NCLS / CPB)) * CPB;
  const float* feats = side ? tf : sf;
  const int* labels = side ? tl : sl;
  float* pn = side ? tpn : spn;

  __shared__ int list[CPB][LCAP];
  __shared__ int s_cnt[CPB];
  __shared__ float s_red[4];
  const int t = threadIdx.x;
  if (t < CPB) s_cnt[t] = 0;
  __syncthreads();

  const int n4 = N >> 2;
  for (int i = t; i < n4; i += 256) {
    int4 lb = ((const int4*)labels)[i];
    unsigned d;
    d = (unsigned)(lb.x - c0); if (d < CPB) { int p = atomicAdd(&s_cnt[d], 1); if (p < LCAP) list[d][p] = 4*i; }
    d = (unsigned)(lb.y - c0); if (d < CPB) { int p = atomicAdd(&s_cnt[d], 1); if (p < LCAP) list[d][p] = 4*i+1; }
    d = (unsigned)(lb.z - c0); if (d < CPB) { int p = atomicAdd(&s_cnt[d], 1); if (p < LCAP) list[d][p] = 4*i+2; }
    d = (unsigned)(lb.w - c0); if (d < CPB) { int p = atomicAdd(&s_cnt[d], 1); if (p < LCAP) list[d][p] = 4*i+3; }
  }
  for (int i = (n4 << 2) + t; i < N; i += 256) {
    unsigned d = (unsigned)(labels[i] - c0);
    if (d < CPB) { int p = atomicAdd(&s_cnt[d], 1); if (p < LCAP) list[d][p] = i; }
  }
  __syncthreads();

  for (int cc = 0; cc < CPB; cc++) {
    const int c = c0 + cc;
    const int m = min(s_cnt[cc], LCAP);
    float s0 = 0.f, s1 = 0.f, s2 = 0.f, s3 = 0.f;
    int i = 0;
    for (; i + 4 <= m; i += 4) {
      s0 += feats[(size_t)list[cc][i]     * DIM + t];
      s1 += feats[(size_t)list[cc][i + 1] * DIM + t];
      s2 += feats[(size_t)list[cc][i + 2] * DIM + t];
      s3 += feats[(size_t)list[cc][i + 3] * DIM + t];
    }
    for (; i < m; i++) s0 += feats[(size_t)list[cc][i] * DIM + t];
    float sum = (s0 + s1) + (s2 + s3);
    float mean = sum / fmaxf((float)m, 1.0f);
    if (!side) mean_out[(size_t)c * DIM + t] = mean;

    float ss = mean * mean;
    #pragma unroll
    for (int o = 1; o < 64; o <<= 1) ss += __shfl_xor(ss, o);
    if ((t & 63) == 0) s_red[t >> 6] = ss;
    __syncthreads();
    float tot = s_red[0] + s_red[1] + s_red[2] + s_red[3];
    float innv = 1.0f / fmaxf(sqrtf(tot), 1e-12f);
    float p = mean * innv;
    pn[(size_t)c * DIM + t] = p;
    if (!side) {
      // tiled bf16 layout: [cf=c/16][kf=k/32][lg=(k/8)&3][col=c&15][e=k&7]
      size_t off = (size_t)(c >> 4) * 4096 + (size_t)(t >> 5) * 512
                 + (size_t)((t >> 3) & 3) * 128 + (size_t)(c & 15) * 8 + (t & 7);
      pbf[off] = (unsigned short)f2bf(p);
    }
    __syncthreads();
  }
}

// ---------------- K2: structure matrices + struct loss (fp32, 64x64 tiles) -----
__global__ __launch_bounds__(256) void struct_kernel(
    const float* __restrict__ spn, const float* __restrict__ tpn,
    float* __restrict__ out_struct, float* __restrict__ acc) {
  __shared__ float Sa[16][68], Sb[16][68], Ta[16][68], Tb[16][68];
  __shared__ float red[256];
  const int t = threadIdx.x;
  const int tx = t & 15, ty = t >> 4;
  const int i0 = blockIdx.y * 64, j0 = blockIdx.x * 64;
  float cs[4][4], cg[4][4];
  #pragma unroll
  for (int a = 0; a < 4; a++)
    #pragma unroll
    for (int b = 0; b < 4; b++) { cs[a][b] = 0.f; cg[a][b] = 0.f; }

  const int srow = t >> 2;
  const int skq = (t & 3) * 4;
  for (int k0 = 0; k0 < DIM; k0 += 16) {
    __syncthreads();
    {
      float4 z = make_float4(0.f, 0.f, 0.f, 0.f);
      int ra = i0 + srow, rb = j0 + srow;
      float4 va = (ra < NCLS) ? *(const float4*)(spn + (size_t)ra * DIM + k0 + skq) : z;
      float4 vb = (rb < NCLS) ? *(const float4*)(spn + (size_t)rb * DIM + k0 + skq) : z;
      float4 wa = (ra < NCLS) ? *(const float4*)(tpn + (size_t)ra * DIM + k0 + skq) : z;
      float4 wb = (rb < NCLS) ? *(const float4*)(tpn + (size_t)rb * DIM + k0 + skq) : z;
      Sa[skq+0][srow]=va.x; Sa[skq+1][srow]=va.y; Sa[skq+2][srow]=va.z; Sa[skq+3][srow]=va.w;
      Sb[skq+0][srow]=vb.x; Sb[skq+1][srow]=vb.y; Sb[skq+2][srow]=vb.z; Sb[skq+3][srow]=vb.w;
      Ta[skq+0][srow]=wa.x; Ta[skq+1][srow]=wa.y; Ta[skq+2][srow]=wa.z; Ta[skq+3][srow]=wa.w;
      Tb[skq+0][srow]=wb.x; Tb[skq+1][srow]=wb.y; Tb[skq+2][srow]=wb.z; Tb[skq+3][srow]=wb.w;
    }
    __syncthreads();
    #pragma unroll
    for (int k = 0; k < 16; k++) {
      float a[4], b[4], c[4], d[4];
      *(float4*)a = *(const float4*)&Sa[k][ty * 4];
      *(float4*)b = *(const float4*)&Sb[k][tx * 4];
      *(float4*)c = *(const float4*)&Ta[k][ty * 4];
      *(float4*)d = *(const float4*)&Tb[k][tx * 4];
      #pragma unroll
      for (int ii = 0; ii < 4; ii++)
        #pragma unroll
        for (int jj = 0; jj < 4; jj++) {
          cs[ii][jj] = fmaf(a[ii], b[jj], cs[ii][jj]);
          cg[ii][jj] = fmaf(c[ii], d[jj], cg[ii][jj]);
        }
    }
  }
  float d2 = 0.f;
  #pragma unroll
  for (int ii = 0; ii < 4; ii++) {
    int gi = i0 + ty * 4 + ii;
    if (gi < NCLS) {
      #pragma unroll
      for (int jj = 0; jj < 4; jj++) {
        int gj = j0 + tx * 4 + jj;
        if (gj < NCLS) {
          out_struct[(size_t)gi * NCLS + gj] = cs[ii][jj];
          float df = cs[ii][jj] - cg[ii][jj];
          d2 += df * df;
        }
      }
    }
  }
  red[t] = d2;
  __syncthreads();
  for (int o = 128; o > 0; o >>= 1) { if (t < o) red[t] += red[t + o]; __syncthreads(); }
  if (t == 0) atomicAdd(acc, red[0]);
}

// ---------------- K3: contrastive loss — MFMA, LDS-staged B, 64 rows/wave ------
__global__ __launch_bounds__(256, 2) void contrast_kernel(
    const float* __restrict__ feats, const int* __restrict__ labels,
    const unsigned short* __restrict__ pbf,
    float* __restrict__ acc_out, int N) {
  __shared__ __align__(16) unsigned short Bt[2][4096];  // 2 x 8KB tiles
  __shared__ float red[256];
  const int t = threadIdx.x;
  const int lane = t & 63, w = t >> 6;
  const int lx = lane & 15, lg = lane >> 4;
  const int row0 = blockIdx.x * 256 + w * 64;
  const float4 z4 = make_float4(0.f, 0.f, 0.f, 0.f);

  short8 af[4][8];
  float sSt[4][4], labD[4][4];
  int mcf[4][4];

  // ---- prologue: load A rows, fold INV_TEMP/||f|| into bf16 fragments ----
  #pragma unroll
  for (int rf = 0; rf < 4; rf++) {
    const int r = row0 + rf * 16 + lx;
    const bool v = r < N;
    const float* rp = feats + (size_t)r * DIM + (lg << 3);
    float4 fx[8], fy[8];
    float n2 = 0.f;
    #pragma unroll
    for (int kf = 0; kf < 8; kf++) {
      fx[kf] = v ? *(const float4*)(rp + kf * 32) : z4;
      fy[kf] = v ? *(const float4*)(rp + kf * 32 + 4) : z4;
      n2 += fx[kf].x*fx[kf].x + fx[kf].y*fx[kf].y + fx[kf].z*fx[kf].z + fx[kf].w*fx[kf].w
          + fy[kf].x*fy[kf].x + fy[kf].y*fy[kf].y + fy[kf].z*fy[kf].z + fy[kf].w*fy[kf].w;
    }
    n2 += __shfl_xor(n2, 16);
    n2 += __shfl_xor(n2, 32);
    const float scl = INV_TEMP / fmaxf(sqrtf(n2), 1e-12f);
    #pragma unroll
    for (int kf = 0; kf < 8; kf++) {
      short8 f;
      f[0] = f2bf(fx[kf].x * scl); f[1] = f2bf(fx[kf].y * scl);
      f[2] = f2bf(fx[kf].z * scl); f[3] = f2bf(fx[kf].w * scl);
      f[4] = f2bf(fy[kf].x * scl); f[5] = f2bf(fy[kf].y * scl);
      f[6] = f2bf(fy[kf].z * scl); f[7] = f2bf(fy[kf].w * scl);
      af[rf][kf] = f;
    }
    #pragma unroll
    for (int reg = 0; reg < 4; reg++) {
      const int row = row0 + rf * 16 + (lg << 2) + reg;
      const int lb = (row < N) ? labels[row] : -1;
      mcf[rf][reg] = (lb >= 0 && (lb & 15) == lx) ? (lb >> 4) : -1;
      sSt[rf][reg] = 0.f;
      labD[rf][reg] = 0.f;
    }
  }

  // ---- stage helper: copy tile cf (8KB) into Bt[buf] (linear, wave-ordered) ----
  #define STAGE(cf_, buf_)                                                        \
    {                                                                             \
      const unsigned short* g0 = pbf + (size_t)(cf_) * 4096 + w * 512 + lane * 8; \
      gload_lds16(g0,        &Bt[buf_][w * 512]);                                 \
      gload_lds16(g0 + 2048, &Bt[buf_][2048 + w * 512]);                          \
    }

  int cur = 0;
  STAGE(0, 0);
  __syncthreads();

  for (int cf = 0; cf < NTILE; cf++) {
    if (cf < NTILE - 1) STAGE(cf + 1, cur ^ 1);

    f32x4 dd[4] = {{0.f,0.f,0.f,0.f},{0.f,0.f,0.f,0.f},{0.f,0.f,0.f,0.f},{0.f,0.f,0.f,0.f}};
    const unsigned short* bb = &Bt[cur][(lg << 7) + (lx << 3)];
    #pragma unroll
    for (int kf = 0; kf < 8; kf++) {
      short8 b = *(const short8*)(bb + (kf << 9));
      dd[0] = __builtin_amdgcn_mfma_f32_16x16x32_bf16(af[0][kf], b, dd[0], 0, 0, 0);
      dd[1] = __builtin_amdgcn_mfma_f32_16x16x32_bf16(af[1][kf], b, dd[1], 0, 0, 0);
      dd[2] = __builtin_amdgcn_mfma_f32_16x16x32_bf16(af[2][kf], b, dd[2], 0, 0, 0);
      dd[3] = __builtin_amdgcn_mfma_f32_16x16x32_bf16(af[3][kf], b, dd[3], 0, 0, 0);
    }
    #pragma unroll
    for (int rf = 0; rf < 4; rf++)
      #pragma unroll
      for (int reg = 0; reg < 4; reg++) {
        const float l = dd[rf][reg];
        sSt[rf][reg] += __expf(l - LSE_C);
        labD[rf][reg] += (mcf[rf][reg] == cf) ? l : 0.f;
      }
    __syncthreads();
    cur ^= 1;
  }

  float wloss = 0.f;
  #pragma unroll
  for (int rf = 0; rf < 4; rf++)
    #pragma unroll
    for (int reg = 0; reg < 4; reg++) {
      float s = sSt[rf][reg], lb = labD[rf][reg];
      #pragma unroll
      for (int o = 1; o < 16; o <<= 1) { s += __shfl_xor(s, o); lb += __shfl_xor(lb, o); }
      const int row = row0 + rf * 16 + (lg << 2) + reg;
      if (lx == 0 && row < N) wloss += LSE_C + __logf(s - PADC) - lb;
    }

  red[t] = wloss;
  __syncthreads();
  for (int o = 128; o > 0; o >>= 1) { if (t < o) red[t] += red[t + o]; __syncthreads(); }
  if (t == 0) atomicAdd(acc_out, red[0]);
}

// ---------------- K4: scalars ---------------------------------------------------
__global__ void final_kernel(const float* __restrict__ acc, float* __restrict__ out, int N) {
  out[0] = acc[0] * (1.0f / (float)(NCLS * NCLS));
  out[1] = acc[1] / (float)N;
}

extern "C" void kernel_launch(void* const* d_in, const int* in_sizes, int n_in,
                              void* d_out, int out_size, void* d_ws, size_t ws_size,
                              hipStream_t stream) {
  const float* src_feats  = (const float*)d_in[0];
  const int*   src_labels = (const int*)d_in[1];
  const float* tgt_feats  = (const float*)d_in[2];
  const int*   tgt_labels = (const int*)d_in[3];
  const int N = in_sizes[0] / DIM;

  // ws layout (floats):
  // [0,2)            acc: [0]=struct sq-sum, [1]=contrast sum
  // [16,256016)      src_pn
  // [256016,512016)  tgt_pn
  // [512016,+129024) pbf: 63 tiles x 8KB bf16, tiled layout
  float* ws = (float*)d_ws;
  float* acc    = ws;
  float* src_pn = ws + 16;
  float* tgt_pn = ws + 256016;
  unsigned short* pbf = (unsigned short*)(ws + 512016);

  float* out_f      = (float*)d_out;
  float* out_protos = out_f + 2;
  float* out_struct = out_f + 2 + NCLS * DIM;

  hipMemsetAsync(acc, 0, 2 * sizeof(float), stream);
  hipMemsetAsync(pbf, 0, (size_t)NTILE * 8192, stream);

  proto_kernel<<<2 * (NCLS / CPB), 256, 0, stream>>>(
      src_feats, src_labels, tgt_feats, tgt_labels, N, out_protos, src_pn, tgt_pn, pbf);

  dim3 sgrid(16, 16);
  struct_kernel<<<sgrid, 256, 0, stream>>>(src_pn, tgt_pn, out_struct, acc);

  int cblocks = (N + 255) / 256;
  contrast_kernel<<<cblocks, 256, 0, stream>>>(src_feats, src_labels, pbf, acc + 1, N);

  final_kernel<<<1, 1, 0, stream>>>(acc, out_f, N);
}

// Round 4
// 430.497 us; speedup vs baseline: 6.4294x; 1.3066x over previous
//
#include <hip/hip_runtime.h>

#define NCLS 1000
#define DIM 256
#define GCAP 500
#define NTILE2 32                 // 32-col tiles over 1024 padded cols
#define SCLF 20.609930f           // 1/(0.07*ln2)
#define CP 23.0f
#define CPLN2 15.94238515f        // 23*ln2
#define LN2 0.69314718056f
#define PADC 2.86102294921875e-06f // 24 * 2^-23 (pad-column contribution)

typedef __attribute__((ext_vector_type(8))) short short8;
typedef __attribute__((ext_vector_type(4))) float f32x4;

__device__ __forceinline__ short f2bf(float f) {
  unsigned u = __float_as_uint(f);
  unsigned r = u + 0x7fffu + ((u >> 16) & 1u);
  return (short)(r >> 16);
}

__device__ __forceinline__ float fexp2(float x) {
#if __has_builtin(__builtin_amdgcn_exp2f)
  return __builtin_amdgcn_exp2f(x);
#else
  return exp2f(x);
#endif
}

__device__ __forceinline__ void gload_lds16(const void* g, void* l) {
  __builtin_amdgcn_global_load_lds(
      (const __attribute__((address_space(1))) unsigned int*)g,
      (__attribute__((address_space(3))) unsigned int*)l, 16, 0, 0);
}

// ---------------- K0: scatter rows into per-class lists ------------------------
__global__ __launch_bounds__(256) void scatter_kernel(
    const int* __restrict__ sl, const int* __restrict__ tl, int N,
    int* __restrict__ gcnt, int* __restrict__ glist) {
  const int i = blockIdx.x * 256 + threadIdx.x;
  if (i >= 2 * N) return;
  const int side = (i >= N) ? 1 : 0;
  const int r = i - side * N;
  const int c = (side ? tl : sl)[r];
  const int bin = side * NCLS + c;
  const int slot = atomicAdd(gcnt + bin, 1);
  if (slot < GCAP) glist[(size_t)bin * GCAP + slot] = r;
}

// ---------------- K1: per-class gather + mean + normalize ----------------------
__global__ __launch_bounds__(256) void proto_kernel(
    const float* __restrict__ sf, const float* __restrict__ tf,
    const int* __restrict__ gcnt, const int* __restrict__ glist,
    float* __restrict__ mean_out, float* __restrict__ spn, float* __restrict__ tpn,
    unsigned short* __restrict__ pbf) {
  const int bid = blockIdx.x;
  const int side = (bid >= NCLS) ? 1 : 0;
  const int c = bid - side * NCLS;
  const float* feats = side ? tf : sf;
  const int* list = glist + (size_t)bid * GCAP;
  const int m = min(gcnt[bid], GCAP);
  const int t = threadIdx.x;
  __shared__ float s_red[4];

  float a0 = 0.f, a1 = 0.f, a2 = 0.f, a3 = 0.f, a4 = 0.f, a5 = 0.f, a6 = 0.f, a7 = 0.f;
  int i = 0;
  for (; i + 8 <= m; i += 8) {
    a0 += feats[(size_t)list[i + 0] * DIM + t];
    a1 += feats[(size_t)list[i + 1] * DIM + t];
    a2 += feats[(size_t)list[i + 2] * DIM + t];
    a3 += feats[(size_t)list[i + 3] * DIM + t];
    a4 += feats[(size_t)list[i + 4] * DIM + t];
    a5 += feats[(size_t)list[i + 5] * DIM + t];
    a6 += feats[(size_t)list[i + 6] * DIM + t];
    a7 += feats[(size_t)list[i + 7] * DIM + t];
  }
  for (; i < m; i++) a0 += feats[(size_t)list[i] * DIM + t];
  const float sum = ((a0 + a1) + (a2 + a3)) + ((a4 + a5) + (a6 + a7));
  const float mean = sum / fmaxf((float)m, 1.0f);
  if (!side) mean_out[(size_t)c * DIM + t] = mean;

  float ss = mean * mean;
  #pragma unroll
  for (int o = 1; o < 64; o <<= 1) ss += __shfl_xor(ss, o);
  if ((t & 63) == 0) s_red[t >> 6] = ss;
  __syncthreads();
  const float tot = s_red[0] + s_red[1] + s_red[2] + s_red[3];
  const float innv = 1.0f / fmaxf(sqrtf(tot), 1e-12f);
  const float p = mean * innv;
  (side ? tpn : spn)[(size_t)c * DIM + t] = p;
  if (!side) {
    // tiled bf16 layout: [c>>4][kf=t>>5][lg=(t>>3)&3][c&15][e=t&7]
    size_t off = (size_t)(c >> 4) * 4096 + (size_t)(t >> 5) * 512
               + (size_t)((t >> 3) & 3) * 128 + (size_t)(c & 15) * 8 + (t & 7);
    pbf[off] = (unsigned short)f2bf(p);
  }
}

// ---------------- K2: structure matrices + struct loss (fp32, 64x64 tiles) -----
__global__ __launch_bounds__(256) void struct_kernel(
    const float* __restrict__ spn, const float* __restrict__ tpn,
    float* __restrict__ out_struct, float* __restrict__ acc) {
  __shared__ float Sa[16][68], Sb[16][68], Ta[16][68], Tb[16][68];
  __shared__ float red[256];
  const int t = threadIdx.x;
  const int tx = t & 15, ty = t >> 4;
  const int i0 = blockIdx.y * 64, j0 = blockIdx.x * 64;
  float cs[4][4], cg[4][4];
  #pragma unroll
  for (int a = 0; a < 4; a++)
    #pragma unroll
    for (int b = 0; b < 4; b++) { cs[a][b] = 0.f; cg[a][b] = 0.f; }

  const int srow = t >> 2;
  const int skq = (t & 3) * 4;
  for (int k0 = 0; k0 < DIM; k0 += 16) {
    __syncthreads();
    {
      float4 z = make_float4(0.f, 0.f, 0.f, 0.f);
      int ra = i0 + srow, rb = j0 + srow;
      float4 va = (ra < NCLS) ? *(const float4*)(spn + (size_t)ra * DIM + k0 + skq) : z;
      float4 vb = (rb < NCLS) ? *(const float4*)(spn + (size_t)rb * DIM + k0 + skq) : z;
      float4 wa = (ra < NCLS) ? *(const float4*)(tpn + (size_t)ra * DIM + k0 + skq) : z;
      float4 wb = (rb < NCLS) ? *(const float4*)(tpn + (size_t)rb * DIM + k0 + skq) : z;
      Sa[skq+0][srow]=va.x; Sa[skq+1][srow]=va.y; Sa[skq+2][srow]=va.z; Sa[skq+3][srow]=va.w;
      Sb[skq+0][srow]=vb.x; Sb[skq+1][srow]=vb.y; Sb[skq+2][srow]=vb.z; Sb[skq+3][srow]=vb.w;
      Ta[skq+0][srow]=wa.x; Ta[skq+1][srow]=wa.y; Ta[skq+2][srow]=wa.z; Ta[skq+3][srow]=wa.w;
      Tb[skq+0][srow]=wb.x; Tb[skq+1][srow]=wb.y; Tb[skq+2][srow]=wb.z; Tb[skq+3][srow]=wb.w;
    }
    __syncthreads();
    #pragma unroll
    for (int k = 0; k < 16; k++) {
      float a[4], b[4], c[4], d[4];
      *(float4*)a = *(const float4*)&Sa[k][ty * 4];
      *(float4*)b = *(const float4*)&Sb[k][tx * 4];
      *(float4*)c = *(const float4*)&Ta[k][ty * 4];
      *(float4*)d = *(const float4*)&Tb[k][tx * 4];
      #pragma unroll
      for (int ii = 0; ii < 4; ii++)
        #pragma unroll
        for (int jj = 0; jj < 4; jj++) {
          cs[ii][jj] = fmaf(a[ii], b[jj], cs[ii][jj]);
          cg[ii][jj] = fmaf(c[ii], d[jj], cg[ii][jj]);
        }
    }
  }
  float d2 = 0.f;
  #pragma unroll
  for (int ii = 0; ii < 4; ii++) {
    int gi = i0 + ty * 4 + ii;
    if (gi < NCLS) {
      #pragma unroll
      for (int jj = 0; jj < 4; jj++) {
        int gj = j0 + tx * 4 + jj;
        if (gj < NCLS) {
          out_struct[(size_t)gi * NCLS + gj] = cs[ii][jj];
          float df = cs[ii][jj] - cg[ii][jj];
          d2 += df * df;
        }
      }
    }
  }
  red[t] = d2;
  __syncthreads();
  for (int o = 128; o > 0; o >>= 1) { if (t < o) red[t] += red[t + o]; __syncthreads(); }
  if (t == 0) atomicAdd(acc, red[0]);
}

// ---------------- K3: contrastive loss — MFMA, 32 rows/wave, 32-col tiles ------
__global__ __launch_bounds__(256, 4) void contrast_kernel(
    const float* __restrict__ feats, const int* __restrict__ labels,
    const unsigned short* __restrict__ pbf,
    float* __restrict__ acc_out, int N) {
  __shared__ __align__(16) unsigned short Bt[2][8192];  // 2 x 16KB tiles (32 cols)
  __shared__ float red[256];
  const int t = threadIdx.x;
  const int lane = t & 63, w = t >> 6;
  const int lx = lane & 15, lg = lane >> 4;
  const int row0 = blockIdx.x * 128 + w * 32;
  const float4 z4 = make_float4(0.f, 0.f, 0.f, 0.f);

  short8 af[2][8];           // 32 rows/wave, unscaled bf16
  float sclF[2][4];          // (INV_TEMP/ln2)/||f|| per owned row
  float sSt[2][4], labD[2][4];
  int code[2][4];            // label's 16-col block index if lx matches, else big

  #pragma unroll
  for (int rf = 0; rf < 2; rf++) {
    const int r = row0 + rf * 16 + lx;
    const bool v = r < N;
    const float* rp = feats + (size_t)r * DIM + (lg << 3);
    float n2 = 0.f;
    #pragma unroll
    for (int kf = 0; kf < 8; kf++) {
      float4 x = v ? *(const float4*)(rp + kf * 32) : z4;
      float4 y = v ? *(const float4*)(rp + kf * 32 + 4) : z4;
      n2 += x.x*x.x + x.y*x.y + x.z*x.z + x.w*x.w
          + y.x*y.x + y.y*y.y + y.z*y.z + y.w*y.w;
      short8 f;
      f[0] = f2bf(x.x); f[1] = f2bf(x.y); f[2] = f2bf(x.z); f[3] = f2bf(x.w);
      f[4] = f2bf(y.x); f[5] = f2bf(y.y); f[6] = f2bf(y.z); f[7] = f2bf(y.w);
      af[rf][kf] = f;
    }
    n2 += __shfl_xor(n2, 16);
    n2 += __shfl_xor(n2, 32);
    const float sw = SCLF / fmaxf(sqrtf(n2), 1e-12f);
    #pragma unroll
    for (int reg = 0; reg < 4; reg++) {
      sclF[rf][reg] = __shfl(sw, (lg << 2) | reg);
      const int row = row0 + rf * 16 + (lg << 2) + reg;
      const int lb = (row < N) ? labels[row] : -1;
      code[rf][reg] = (lb >= 0 && (lb & 15) == lx) ? (lb >> 4) : 0x7fff;
      sSt[rf][reg] = 0.f;
      labD[rf][reg] = 0.f;
    }
  }

  // stage a 16KB tile (8192 ushorts): per wave 4 x 1KB linear copies
  #define STAGE(cf_, buf_)                                                          \
    {                                                                               \
      const unsigned short* g0 = pbf + ((size_t)(cf_) << 13) + (w << 9) + (lane << 3); \
      _Pragma("unroll")                                                             \
      for (int q = 0; q < 4; q++)                                                   \
        gload_lds16(g0 + (q << 11), &Bt[buf_][(q << 11) + (w << 9)]);               \
    }

  int cur = 0;
  STAGE(0, 0);
  __syncthreads();

  for (int cf = 0; cf < NTILE2; cf++) {
    if (cf < NTILE2 - 1) STAGE(cf + 1, cur ^ 1);

    f32x4 dd[2][2];
    #pragma unroll
    for (int a = 0; a < 2; a++)
      #pragma unroll
      for (int b = 0; b < 2; b++) dd[a][b] = (f32x4){0.f, 0.f, 0.f, 0.f};

    const unsigned short* bb = &Bt[cur][(lg << 7) + (lx << 3)];
    #pragma unroll
    for (int kf = 0; kf < 8; kf++) {
      short8 b0 = *(const short8*)(bb + (kf << 9));
      short8 b1 = *(const short8*)(bb + 4096 + (kf << 9));
      dd[0][0] = __builtin_amdgcn_mfma_f32_16x16x32_bf16(af[0][kf], b0, dd[0][0], 0, 0, 0);
      dd[1][0] = __builtin_amdgcn_mfma_f32_16x16x32_bf16(af[1][kf], b0, dd[1][0], 0, 0, 0);
      dd[0][1] = __builtin_amdgcn_mfma_f32_16x16x32_bf16(af[0][kf], b1, dd[0][1], 0, 0, 0);
      dd[1][1] = __builtin_amdgcn_mfma_f32_16x16x32_bf16(af[1][kf], b1, dd[1][1], 0, 0, 0);
    }
    #pragma unroll
    for (int rf = 0; rf < 2; rf++)
      #pragma unroll
      for (int reg = 0; reg < 4; reg++) {
        const float a0 = fmaf(dd[rf][0][reg], sclF[rf][reg], -CP);
        const float a1 = fmaf(dd[rf][1][reg], sclF[rf][reg], -CP);
        sSt[rf][reg] += fexp2(a0) + fexp2(a1);
        labD[rf][reg] += (code[rf][reg] == 2 * cf)     ? dd[rf][0][reg] : 0.f;
        labD[rf][reg] += (code[rf][reg] == 2 * cf + 1) ? dd[rf][1][reg] : 0.f;
      }
    __syncthreads();
    cur ^= 1;
  }

  float wloss = 0.f;
  #pragma unroll
  for (int rf = 0; rf < 2; rf++)
    #pragma unroll
    for (int reg = 0; reg < 4; reg++) {
      float s = sSt[rf][reg], lb = labD[rf][reg];
      #pragma unroll
      for (int o = 1; o < 16; o <<= 1) { s += __shfl_xor(s, o); lb += __shfl_xor(lb, o); }
      const int row = row0 + rf * 16 + (lg << 2) + reg;
      if (lx == 0 && row < N)
        wloss += logf(s - PADC) + CPLN2 - lb * sclF[rf][reg] * LN2;
    }

  red[t] = wloss;
  __syncthreads();
  for (int o = 128; o > 0; o >>= 1) { if (t < o) red[t] += red[t + o]; __syncthreads(); }
  if (t == 0) atomicAdd(acc_out, red[0]);
}

// ---------------- K4: scalars ---------------------------------------------------
__global__ void final_kernel(const float* __restrict__ acc, float* __restrict__ out, int N) {
  out[0] = acc[0] * (1.0f / (float)(NCLS * NCLS));
  out[1] = acc[1] / (float)N;
}

extern "C" void kernel_launch(void* const* d_in, const int* in_sizes, int n_in,
                              void* d_out, int out_size, void* d_ws, size_t ws_size,
                              hipStream_t stream) {
  const float* src_feats  = (const float*)d_in[0];
  const int*   src_labels = (const int*)d_in[1];
  const float* tgt_feats  = (const float*)d_in[2];
  const int*   tgt_labels = (const int*)d_in[3];
  const int N = in_sizes[0] / DIM;

  // ws layout (floats):
  // [0,16)           acc: [0]=struct sq-sum, [1]=contrast sum
  // [16,256016)      src_pn
  // [256016,512016)  tgt_pn
  // [512016,643088)  pbf: 64 blocks x 4096 ushorts (1024 padded cols)
  // [643088,645088)  gcnt: 2000 ints
  float* ws = (float*)d_ws;
  float* acc    = ws;
  float* src_pn = ws + 16;
  float* tgt_pn = ws + 256016;
  unsigned short* pbf = (unsigned short*)(ws + 512016);
  int* gcnt = (int*)(ws + 643088);

  float* out_f      = (float*)d_out;
  float* out_protos = out_f + 2;
  float* out_struct = out_f + 2 + NCLS * DIM;
  // glist borrows the out_struct region (1M ints); struct_kernel overwrites it later
  int* glist = (int*)out_struct;

  hipMemsetAsync(acc, 0, 2 * sizeof(float), stream);
  hipMemsetAsync(gcnt, 0, 2 * NCLS * sizeof(int), stream);
  hipMemsetAsync(pbf + 62 * 4096, 0, 2 * 4096 * sizeof(unsigned short), stream);

  int sblocks = (2 * N + 255) / 256;
  scatter_kernel<<<sblocks, 256, 0, stream>>>(src_labels, tgt_labels, N, gcnt, glist);

  proto_kernel<<<2 * NCLS, 256, 0, stream>>>(src_feats, tgt_feats, gcnt, glist,
                                             out_protos, src_pn, tgt_pn, pbf);

  dim3 sgrid(16, 16);
  struct_kernel<<<sgrid, 256, 0, stream>>>(src_pn, tgt_pn, out_struct, acc);

  int cblocks = (N + 127) / 128;
  contrast_kernel<<<cblocks, 256, 0, stream>>>(src_feats, src_labels, pbf, acc + 1, N);

  final_kernel<<<1, 1, 0, stream>>>(acc, out_f, N);
}

// Round 5
// 423.296 us; speedup vs baseline: 6.5388x; 1.0170x over previous
//
#include <hip/hip_runtime.h>

#define NCLS 1000
#define DIM 256
#define GCAP 500
#define NHALF 64                  // 64 half-tiles of 16 cols over 1024 padded cols
#define SCLF 20.609930f           // 1/(0.07*ln2)
#define CP 23.0f
#define CPLN2 15.94238515f        // 23*ln2
#define LN2 0.69314718056f
#define PADC 2.86102294921875e-06f // 24 * 2^-23 (pad-column contribution)

typedef __attribute__((ext_vector_type(8))) short short8;
typedef __attribute__((ext_vector_type(4))) float f32x4;

__device__ __forceinline__ short f2bf(float f) {
  unsigned u = __float_as_uint(f);
  unsigned r = u + 0x7fffu + ((u >> 16) & 1u);
  return (short)(r >> 16);
}

__device__ __forceinline__ float fexp2(float x) {
#if __has_builtin(__builtin_amdgcn_exp2f)
  return __builtin_amdgcn_exp2f(x);
#else
  return exp2f(x);
#endif
}

__device__ __forceinline__ void gload_lds16(const void* g, void* l) {
  __builtin_amdgcn_global_load_lds(
      (const __attribute__((address_space(1))) unsigned int*)g,
      (__attribute__((address_space(3))) unsigned int*)l, 16, 0, 0);
}

// ---------------- K0: scatter rows into per-class lists ------------------------
__global__ __launch_bounds__(256) void scatter_kernel(
    const int* __restrict__ sl, const int* __restrict__ tl, int N,
    int* __restrict__ gcnt, int* __restrict__ glist) {
  const int i = blockIdx.x * 256 + threadIdx.x;
  if (i >= 2 * N) return;
  const int side = (i >= N) ? 1 : 0;
  const int r = i - side * N;
  const int c = (side ? tl : sl)[r];
  const int bin = side * NCLS + c;
  const int slot = atomicAdd(gcnt + bin, 1);
  if (slot < GCAP) glist[(size_t)bin * GCAP + slot] = r;
}

// ---------------- K1: per-class gather + mean + normalize ----------------------
__global__ __launch_bounds__(256) void proto_kernel(
    const float* __restrict__ sf, const float* __restrict__ tf,
    const int* __restrict__ gcnt, const int* __restrict__ glist,
    float* __restrict__ mean_out, float* __restrict__ spn, float* __restrict__ tpn,
    unsigned short* __restrict__ pbf) {
  const int bid = blockIdx.x;
  const int side = (bid >= NCLS) ? 1 : 0;
  const int c = bid - side * NCLS;
  const float* feats = side ? tf : sf;
  const int* list = glist + (size_t)bid * GCAP;
  const int m = min(gcnt[bid], GCAP);
  const int t = threadIdx.x;
  __shared__ float s_red[4];

  float a0 = 0.f, a1 = 0.f, a2 = 0.f, a3 = 0.f, a4 = 0.f, a5 = 0.f, a6 = 0.f, a7 = 0.f;
  int i = 0;
  for (; i + 8 <= m; i += 8) {
    a0 += feats[(size_t)list[i + 0] * DIM + t];
    a1 += feats[(size_t)list[i + 1] * DIM + t];
    a2 += feats[(size_t)list[i + 2] * DIM + t];
    a3 += feats[(size_t)list[i + 3] * DIM + t];
    a4 += feats[(size_t)list[i + 4] * DIM + t];
    a5 += feats[(size_t)list[i + 5] * DIM + t];
    a6 += feats[(size_t)list[i + 6] * DIM + t];
    a7 += feats[(size_t)list[i + 7] * DIM + t];
  }
  for (; i < m; i++) a0 += feats[(size_t)list[i] * DIM + t];
  const float sum = ((a0 + a1) + (a2 + a3)) + ((a4 + a5) + (a6 + a7));
  const float mean = sum / fmaxf((float)m, 1.0f);
  if (!side) mean_out[(size_t)c * DIM + t] = mean;

  float ss = mean * mean;
  #pragma unroll
  for (int o = 1; o < 64; o <<= 1) ss += __shfl_xor(ss, o);
  if ((t & 63) == 0) s_red[t >> 6] = ss;
  __syncthreads();
  const float tot = s_red[0] + s_red[1] + s_red[2] + s_red[3];
  const float innv = 1.0f / fmaxf(sqrtf(tot), 1e-12f);
  const float p = mean * innv;
  (side ? tpn : spn)[(size_t)c * DIM + t] = p;
  if (!side) {
    // tiled bf16 layout: [c>>4][kf=t>>5][lg=(t>>3)&3][c&15][e=t&7]
    size_t off = (size_t)(c >> 4) * 4096 + (size_t)(t >> 5) * 512
               + (size_t)((t >> 3) & 3) * 128 + (size_t)(c & 15) * 8 + (t & 7);
    pbf[off] = (unsigned short)f2bf(p);
  }
}

// ---------------- K2: structure matrices + struct loss (fp32, 64x64 tiles) -----
__global__ __launch_bounds__(256) void struct_kernel(
    const float* __restrict__ spn, const float* __restrict__ tpn,
    float* __restrict__ out_struct, float* __restrict__ acc) {
  __shared__ float Sa[16][68], Sb[16][68], Ta[16][68], Tb[16][68];
  __shared__ float red[256];
  const int t = threadIdx.x;
  const int tx = t & 15, ty = t >> 4;
  const int i0 = blockIdx.y * 64, j0 = blockIdx.x * 64;
  float cs[4][4], cg[4][4];
  #pragma unroll
  for (int a = 0; a < 4; a++)
    #pragma unroll
    for (int b = 0; b < 4; b++) { cs[a][b] = 0.f; cg[a][b] = 0.f; }

  const int srow = t >> 2;
  const int skq = (t & 3) * 4;
  for (int k0 = 0; k0 < DIM; k0 += 16) {
    __syncthreads();
    {
      float4 z = make_float4(0.f, 0.f, 0.f, 0.f);
      int ra = i0 + srow, rb = j0 + srow;
      float4 va = (ra < NCLS) ? *(const float4*)(spn + (size_t)ra * DIM + k0 + skq) : z;
      float4 vb = (rb < NCLS) ? *(const float4*)(spn + (size_t)rb * DIM + k0 + skq) : z;
      float4 wa = (ra < NCLS) ? *(const float4*)(tpn + (size_t)ra * DIM + k0 + skq) : z;
      float4 wb = (rb < NCLS) ? *(const float4*)(tpn + (size_t)rb * DIM + k0 + skq) : z;
      Sa[skq+0][srow]=va.x; Sa[skq+1][srow]=va.y; Sa[skq+2][srow]=va.z; Sa[skq+3][srow]=va.w;
      Sb[skq+0][srow]=vb.x; Sb[skq+1][srow]=vb.y; Sb[skq+2][srow]=vb.z; Sb[skq+3][srow]=vb.w;
      Ta[skq+0][srow]=wa.x; Ta[skq+1][srow]=wa.y; Ta[skq+2][srow]=wa.z; Ta[skq+3][srow]=wa.w;
      Tb[skq+0][srow]=wb.x; Tb[skq+1][srow]=wb.y; Tb[skq+2][srow]=wb.z; Tb[skq+3][srow]=wb.w;
    }
    __syncthreads();
    #pragma unroll
    for (int k = 0; k < 16; k++) {
      float a[4], b[4], c[4], d[4];
      *(float4*)a = *(const float4*)&Sa[k][ty * 4];
      *(float4*)b = *(const float4*)&Sb[k][tx * 4];
      *(float4*)c = *(const float4*)&Ta[k][ty * 4];
      *(float4*)d = *(const float4*)&Tb[k][tx * 4];
      #pragma unroll
      for (int ii = 0; ii < 4; ii++)
        #pragma unroll
        for (int jj = 0; jj < 4; jj++) {
          cs[ii][jj] = fmaf(a[ii], b[jj], cs[ii][jj]);
          cg[ii][jj] = fmaf(c[ii], d[jj], cg[ii][jj]);
        }
    }
  }
  float d2 = 0.f;
  #pragma unroll
  for (int ii = 0; ii < 4; ii++) {
    int gi = i0 + ty * 4 + ii;
    if (gi < NCLS) {
      #pragma unroll
      for (int jj = 0; jj < 4; jj++) {
        int gj = j0 + tx * 4 + jj;
        if (gj < NCLS) {
          out_struct[(size_t)gi * NCLS + gj] = cs[ii][jj];
          float df = cs[ii][jj] - cg[ii][jj];
          d2 += df * df;
        }
      }
    }
  }
  red[t] = d2;
  __syncthreads();
  for (int o = 128; o > 0; o >>= 1) { if (t < o) red[t] += red[t + o]; __syncthreads(); }
  if (t == 0) atomicAdd(acc, red[0]);
}

// ------- K3: contrastive loss — MFMA, ring-4 LDS, counted vmcnt (T3+T4+T5) -----
__global__ __launch_bounds__(256, 4) void contrast_kernel(
    const float* __restrict__ feats, const int* __restrict__ labels,
    const unsigned short* __restrict__ pbf,
    float* __restrict__ acc_out, int N) {
  __shared__ __align__(16) unsigned short Bt[4][4096];  // ring of 4 x 8KB half-tiles
  __shared__ float red[256];
  const int t = threadIdx.x;
  const int lane = t & 63, w = t >> 6;
  const int lx = lane & 15, lg = lane >> 4;
  const int row0 = blockIdx.x * 128 + w * 32;
  const float4 z4 = make_float4(0.f, 0.f, 0.f, 0.f);

  short8 af[2][8];           // 32 rows/wave, unscaled bf16
  float sclF[2][4];          // (1/(T*ln2))/||f|| per owned row
  float sSt[2][4], labD[2][4];
  int code[2][4];            // label's 16-col half-tile index if lx matches, else big

  #pragma unroll
  for (int rf = 0; rf < 2; rf++) {
    const int r = row0 + rf * 16 + lx;
    const bool v = r < N;
    const float* rp = feats + (size_t)r * DIM + (lg << 3);
    float n2 = 0.f;
    #pragma unroll
    for (int kf = 0; kf < 8; kf++) {
      float4 x = v ? *(const float4*)(rp + kf * 32) : z4;
      float4 y = v ? *(const float4*)(rp + kf * 32 + 4) : z4;
      n2 += x.x*x.x + x.y*x.y + x.z*x.z + x.w*x.w
          + y.x*y.x + y.y*y.y + y.z*y.z + y.w*y.w;
      short8 f;
      f[0] = f2bf(x.x); f[1] = f2bf(x.y); f[2] = f2bf(x.z); f[3] = f2bf(x.w);
      f[4] = f2bf(y.x); f[5] = f2bf(y.y); f[6] = f2bf(y.z); f[7] = f2bf(y.w);
      af[rf][kf] = f;
    }
    n2 += __shfl_xor(n2, 16);
    n2 += __shfl_xor(n2, 32);
    const float sw = SCLF / fmaxf(sqrtf(n2), 1e-12f);
    #pragma unroll
    for (int reg = 0; reg < 4; reg++) {
      sclF[rf][reg] = __shfl(sw, (lg << 2) | reg);
      const int row = row0 + rf * 16 + (lg << 2) + reg;
      const int lb = (row < N) ? labels[row] : -1;
      code[rf][reg] = (lb >= 0 && (lb & 15) == lx) ? (lb >> 4) : 0x7fff;
      sSt[rf][reg] = 0.f;
      labD[rf][reg] = 0.f;
    }
  }

  // stage half-tile h (16 cols, 8KB) into ring slot s: 2x1KB linear copies/wave
  #define STAGEH(h_, s_)                                                             \
    {                                                                                \
      const unsigned short* g0 = pbf + ((size_t)(h_) << 12) + (w << 9) + (lane << 3);\
      gload_lds16(g0,        &Bt[s_][(w << 9)]);                                     \
      gload_lds16(g0 + 2048, &Bt[s_][2048 + (w << 9)]);                              \
    }

  STAGEH(0, 0);
  STAGEH(1, 1);

  for (int h = 0; h < NHALF; h++) {
    if (h < NHALF - 2) {
      STAGEH(h + 2, (h + 2) & 3);
      asm volatile("s_waitcnt vmcnt(4)" ::: "memory");   // stage h retired; h+1,h+2 in flight
    } else if (h == NHALF - 2) {
      asm volatile("s_waitcnt vmcnt(2)" ::: "memory");
    } else {
      asm volatile("s_waitcnt vmcnt(0)" ::: "memory");
    }
    __builtin_amdgcn_s_barrier();
    __builtin_amdgcn_sched_barrier(0);   // pin LDS reads below the barrier (rule 18)

    const unsigned short* bb = &Bt[h & 3][(lg << 7) + (lx << 3)];
    f32x4 d0 = {0.f, 0.f, 0.f, 0.f};
    f32x4 d1 = {0.f, 0.f, 0.f, 0.f};
    __builtin_amdgcn_s_setprio(1);
    #pragma unroll
    for (int kf = 0; kf < 8; kf++) {
      short8 b = *(const short8*)(bb + (kf << 9));
      d0 = __builtin_amdgcn_mfma_f32_16x16x32_bf16(af[0][kf], b, d0, 0, 0, 0);
      d1 = __builtin_amdgcn_mfma_f32_16x16x32_bf16(af[1][kf], b, d1, 0, 0, 0);
    }
    __builtin_amdgcn_s_setprio(0);

    #pragma unroll
    for (int reg = 0; reg < 4; reg++) {
      const float a0 = fmaf(d0[reg], sclF[0][reg], -CP);
      const float a1 = fmaf(d1[reg], sclF[1][reg], -CP);
      sSt[0][reg] += fexp2(a0);
      sSt[1][reg] += fexp2(a1);
      labD[0][reg] += (code[0][reg] == h) ? d0[reg] : 0.f;
      labD[1][reg] += (code[1][reg] == h) ? d1[reg] : 0.f;
    }
  }

  float wloss = 0.f;
  #pragma unroll
  for (int rf = 0; rf < 2; rf++)
    #pragma unroll
    for (int reg = 0; reg < 4; reg++) {
      float s = sSt[rf][reg], lb = labD[rf][reg];
      #pragma unroll
      for (int o = 1; o < 16; o <<= 1) { s += __shfl_xor(s, o); lb += __shfl_xor(lb, o); }
      const int row = row0 + rf * 16 + (lg << 2) + reg;
      if (lx == 0 && row < N)
        wloss += logf(s - PADC) + CPLN2 - lb * sclF[rf][reg] * LN2;
    }

  red[t] = wloss;
  __syncthreads();
  for (int o = 128; o > 0; o >>= 1) { if (t < o) red[t] += red[t + o]; __syncthreads(); }
  if (t == 0) atomicAdd(acc_out, red[0]);
}

// ---------------- K4: scalars ---------------------------------------------------
__global__ void final_kernel(const float* __restrict__ acc, float* __restrict__ out, int N) {
  out[0] = acc[0] * (1.0f / (float)(NCLS * NCLS));
  out[1] = acc[1] / (float)N;
}

extern "C" void kernel_launch(void* const* d_in, const int* in_sizes, int n_in,
                              void* d_out, int out_size, void* d_ws, size_t ws_size,
                              hipStream_t stream) {
  const float* src_feats  = (const float*)d_in[0];
  const int*   src_labels = (const int*)d_in[1];
  const float* tgt_feats  = (const float*)d_in[2];
  const int*   tgt_labels = (const int*)d_in[3];
  const int N = in_sizes[0] / DIM;

  // ws layout (floats):
  // [0,16)           acc: [0]=struct sq-sum, [1]=contrast sum
  // [16,256016)      src_pn
  // [256016,512016)  tgt_pn
  // [512016,643088)  pbf: 64 blocks x 4096 ushorts (1024 padded cols)
  // [643088,645088)  gcnt: 2000 ints
  float* ws = (float*)d_ws;
  float* acc    = ws;
  float* src_pn = ws + 16;
  float* tgt_pn = ws + 256016;
  unsigned short* pbf = (unsigned short*)(ws + 512016);
  int* gcnt = (int*)(ws + 643088);

  float* out_f      = (float*)d_out;
  float* out_protos = out_f + 2;
  float* out_struct = out_f + 2 + NCLS * DIM;
  // glist borrows the out_struct region (1M ints); struct_kernel overwrites it later
  int* glist = (int*)out_struct;

  hipMemsetAsync(acc, 0, 2 * sizeof(float), stream);
  hipMemsetAsync(gcnt, 0, 2 * NCLS * sizeof(int), stream);
  hipMemsetAsync(pbf + 62 * 4096, 0, 2 * 4096 * sizeof(unsigned short), stream);

  int sblocks = (2 * N + 255) / 256;
  scatter_kernel<<<sblocks, 256, 0, stream>>>(src_labels, tgt_labels, N, gcnt, glist);

  proto_kernel<<<2 * NCLS, 256, 0, stream>>>(src_feats, tgt_feats, gcnt, glist,
                                             out_protos, src_pn, tgt_pn, pbf);

  dim3 sgrid(16, 16);
  struct_kernel<<<sgrid, 256, 0, stream>>>(src_pn, tgt_pn, out_struct, acc);

  int cblocks = (N + 127) / 128;
  contrast_kernel<<<cblocks, 256, 0, stream>>>(src_feats, src_labels, pbf, acc + 1, N);

  final_kernel<<<1, 1, 0, stream>>>(acc, out_f, N);
}